// Round 9
// baseline (754.986 us; speedup 1.0000x reference)
//
#include <hip/hip_runtime.h>
#include <hip/hip_bf16.h>

typedef __attribute__((ext_vector_type(8))) __bf16 bf16x8;
typedef __attribute__((ext_vector_type(4))) float f32x4;

#define MDIM 16384  // B*T
#define HDIM 2048
#define IDIM 512
#define ODIM 512
#define SCAP 512    // per-bin candidate cap

static __device__ __forceinline__ unsigned short f2bf(float f) {
  unsigned int u = __float_as_uint(f);
  unsigned int r = (u + 0x7fffu + ((u >> 16) & 1u)) >> 16;
  return (unsigned short)r;
}

static __device__ __forceinline__ uint4 pack8bf(float4 x, float4 y) {
  uint4 o;
  o.x = (unsigned int)f2bf(x.x) | ((unsigned int)f2bf(x.y) << 16);
  o.y = (unsigned int)f2bf(x.z) | ((unsigned int)f2bf(x.w) << 16);
  o.z = (unsigned int)f2bf(y.x) | ((unsigned int)f2bf(y.y) << 16);
  o.w = (unsigned int)f2bf(y.z) | ((unsigned int)f2bf(y.w) << 16);
  return o;
}

// ---------------- GEMM1: h = x @ W_enc^T + b_enc (f32) ----------------
// Round-0 version exactly: 128x128 tile, BK=32, 8x8 micro-tile, NO prefetch.
// Measured 381-396 us (4 runs), VGPR 72, VALU 77%. This is the LDS/VALU
// co-saturation equilibrium (per k-step both pipes need 32 cyc/wave at CU
// level); bigger micro-tiles spill (measured 2x). Do not touch.
__global__ __launch_bounds__(256) void gemm1_kernel(
    const float* __restrict__ x,     // [M, IDIM]
    const float* __restrict__ wenc,  // [HDIM, IDIM]
    const float* __restrict__ benc,  // [HDIM]
    float* __restrict__ h) {         // [M, HDIM]
  __shared__ __align__(16) float As[32][132];  // [k][m], +4 pad
  __shared__ __align__(16) float Bs[32][132];  // [k][n]
  const int t = threadIdx.x;
  const int tx = t & 15, ty = t >> 4;
  const int m0 = blockIdx.y * 128;
  const int n0 = blockIdx.x * 128;
  const int r0 = t >> 1;          // 0..127 staging row
  const int kh = (t & 1) * 16;    // k sub-offset (0 or 16)

  const float* pa = x + (size_t)(m0 + r0) * IDIM + kh;
  const float* pb = wenc + (size_t)(n0 + r0) * IDIM + kh;

  float acc[8][8];
#pragma unroll
  for (int i = 0; i < 8; ++i)
#pragma unroll
    for (int j = 0; j < 8; ++j) acc[i][j] = 0.f;

  for (int kt = 0; kt < IDIM; kt += 32) {
    float4 a0 = *(const float4*)(pa + kt);
    float4 a1 = *(const float4*)(pa + kt + 4);
    float4 a2 = *(const float4*)(pa + kt + 8);
    float4 a3 = *(const float4*)(pa + kt + 12);
    float4 b0 = *(const float4*)(pb + kt);
    float4 b1 = *(const float4*)(pb + kt + 4);
    float4 b2 = *(const float4*)(pb + kt + 8);
    float4 b3 = *(const float4*)(pb + kt + 12);
    __syncthreads();
    {
      const float av[16] = {a0.x, a0.y, a0.z, a0.w, a1.x, a1.y, a1.z, a1.w,
                            a2.x, a2.y, a2.z, a2.w, a3.x, a3.y, a3.z, a3.w};
      const float bv[16] = {b0.x, b0.y, b0.z, b0.w, b1.x, b1.y, b1.z, b1.w,
                            b2.x, b2.y, b2.z, b2.w, b3.x, b3.y, b3.z, b3.w};
#pragma unroll
      for (int j = 0; j < 16; ++j) {
        As[kh + j][r0] = av[j];
        Bs[kh + j][r0] = bv[j];
      }
    }
    __syncthreads();
#pragma unroll
    for (int k = 0; k < 32; ++k) {
      float4 av0 = *(const float4*)&As[k][ty * 4];
      float4 av1 = *(const float4*)&As[k][64 + ty * 4];
      float4 bv0 = *(const float4*)&Bs[k][tx * 4];
      float4 bv1 = *(const float4*)&Bs[k][64 + tx * 4];
      float am[8] = {av0.x, av0.y, av0.z, av0.w, av1.x, av1.y, av1.z, av1.w};
      float bm[8] = {bv0.x, bv0.y, bv0.z, bv0.w, bv1.x, bv1.y, bv1.z, bv1.w};
#pragma unroll
      for (int i = 0; i < 8; ++i)
#pragma unroll
        for (int j = 0; j < 8; ++j) acc[i][j] += am[i] * bm[j];
    }
  }
  float4 be0 = *(const float4*)(benc + n0 + tx * 4);
  float4 be1 = *(const float4*)(benc + n0 + 64 + tx * 4);
  float bb[8] = {be0.x, be0.y, be0.z, be0.w, be1.x, be1.y, be1.z, be1.w};
#pragma unroll
  for (int i = 0; i < 8; ++i) {
    int m = m0 + ((i < 4) ? (ty * 4 + i) : (64 + ty * 4 + (i - 4)));
    float* hrow = h + (size_t)m * HDIM + n0;
    float4 s0 = {acc[i][0] + bb[0], acc[i][1] + bb[1], acc[i][2] + bb[2], acc[i][3] + bb[3]};
    float4 s1 = {acc[i][4] + bb[4], acc[i][5] + bb[5], acc[i][6] + bb[6], acc[i][7] + bb[7]};
    *(float4*)(hrow + tx * 4) = s0;
    *(float4*)(hrow + 64 + tx * 4) = s1;
  }
}

// ---------------- selection v5: wave-per-row, barrier-free ------------------
// v4 (measured 123 us) + two VALU cuts:
//  (a) refine candidates cached in 4 regs (0-padded; 0 never >= cth since
//      cth >= 1) -> 21-bit loop is LDS-free for C<=128 (typical C ~ 50-150);
//  (b) tie fast path: when #(key==v) == remaining budget (the common case),
//      selection == (key >= v) and the 8x prefix-scan rank phase is skipped.
//      v==0 degenerate case provably never takes the fast path (e512 =
//      2048-g != 512-g) -> falls to the verified rank logic.
__global__ __launch_bounds__(256, 4) void select_kernel(
    float* __restrict__ hbuf,           // in: raw h [M,HDIM]; out: mask_prev_new
    const int* __restrict__ maskp,      // [M, HDIM]
    unsigned short* __restrict__ hs) {  // out: h*mask_share as bf16 [M,HDIM]
  const int t = threadIdx.x;
  const int lane = t & 63;
  const int w = t >> 6;
  const int row = blockIdx.x * 4 + w;

  __shared__ int hist[4][1024];               // 16 KB, wave-private slices
  __shared__ unsigned int cand[4][2][SCAP];   // 16 KB
  __shared__ int nc[4][2];

  int* H = hist[w];
  float* hrow = hbuf + (size_t)row * HDIM;
  const int* mrow = maskp + (size_t)row * HDIM;
  unsigned short* hsrow = hs + (size_t)row * HDIM;

  {
    int4 z = {0, 0, 0, 0};
#pragma unroll
    for (int i = 0; i < 4; ++i) *(int4*)&H[(i * 64 + lane) * 4] = z;
  }
  if (lane == 0) { nc[w][0] = 0; nc[w][1] = 0; }

  unsigned int key[8][4];
  uint2 hvb[8];
  unsigned int mmbits = 0;
#pragma unroll
  for (int s = 0; s < 8; ++s) {
    float4 hv = *(const float4*)(hrow + (s * 64 + lane) * 4);
    int4 mv = *(const int4*)(mrow + (s * 64 + lane) * 4);
    float h0 = (mv.x > 0) ? 0.f : hv.x;
    float h1 = (mv.y > 0) ? 0.f : hv.y;
    float h2 = (mv.z > 0) ? 0.f : hv.z;
    float h3 = (mv.w > 0) ? 0.f : hv.w;
    mmbits |= ((mv.x > 0) ? 1u : 0u) << (s * 4 + 0);
    mmbits |= ((mv.y > 0) ? 1u : 0u) << (s * 4 + 1);
    mmbits |= ((mv.z > 0) ? 1u : 0u) << (s * 4 + 2);
    mmbits |= ((mv.w > 0) ? 1u : 0u) << (s * 4 + 3);
    key[s][0] = __float_as_uint(h0 * h0);
    key[s][1] = __float_as_uint(h1 * h1);
    key[s][2] = __float_as_uint(h2 * h2);
    key[s][3] = __float_as_uint(h3 * h3);
    hvb[s].x = (unsigned int)f2bf(h0) | ((unsigned int)f2bf(h1) << 16);
    hvb[s].y = (unsigned int)f2bf(h2) | ((unsigned int)f2bf(h3) << 16);
  }

#pragma unroll
  for (int s = 0; s < 8; ++s)
#pragma unroll
    for (int c = 0; c < 4; ++c)
      if (key[s][c]) atomicAdd(&H[key[s][c] >> 21], 1);

  int q[16];
#pragma unroll
  for (int i = 0; i < 16; i += 4) {
    int4 hh = *(const int4*)&H[lane * 16 + i];
    q[i] = hh.x; q[i + 1] = hh.y; q[i + 2] = hh.z; q[i + 3] = hh.w;
  }
  int ls = 0;
#pragma unroll
  for (int i = 0; i < 16; ++i) ls += q[i];
  int rs = ls;
#pragma unroll
  for (int d = 1; d < 64; d <<= 1) {
    int o = __shfl_down(rs, d, 64);
    rs += (lane + d < 64) ? o : 0;
  }
  int f512 = -1, f256 = -1;
  {
    int c = rs - ls;
#pragma unroll
    for (int i = 15; i >= 0; --i) {
      int hc = q[i];
      if (c < 512 && c + hc >= 512) f512 = ((lane * 16 + i) << 12) | (512 - c);
      if (c < 256 && c + hc >= 256) f256 = ((lane * 16 + i) << 12) | (256 - c);
      c += hc;
    }
  }
#pragma unroll
  for (int d = 1; d < 64; d <<= 1) {
    f512 = max(f512, __shfl_xor(f512, d, 64));
    f256 = max(f256, __shfl_xor(f256, d, 64));
  }
  int b512, rb512, b256, rb256;
  if (f512 < 0) { b512 = 0; rb512 = 0x40000000; } else { b512 = f512 >> 12; rb512 = f512 & 0xfff; }
  if (f256 < 0) { b256 = 0; rb256 = 0x40000000; } else { b256 = f256 >> 12; rb256 = f256 & 0xfff; }

  unsigned int* c5 = cand[w][0];
  unsigned int* c2 = cand[w][1];
#pragma unroll
  for (int s = 0; s < 8; ++s)
#pragma unroll
    for (int c = 0; c < 4; ++c) {
      unsigned int k = key[s][c];
      if (k) {
        int bin = (int)(k >> 21);
        if (bin == b512) { int p = atomicAdd(&nc[w][0], 1); if (p < SCAP) c5[p] = k; }
        if (bin == b256) { int p = atomicAdd(&nc[w][1], 1); if (p < SCAP) c2[p] = k; }
      }
    }
  int C5 = nc[w][0]; C5 = (C5 < SCAP) ? C5 : SCAP;
  int C2 = nc[w][1]; C2 = (C2 < SCAP) ? C2 : SCAP;

  const int half = lane >> 5;
  const int hl = lane & 31;
  unsigned int bb = half ? (unsigned int)b256 : (unsigned int)b512;
  int rr = half ? rb256 : rb512;
  const unsigned int* cd = half ? c2 : c5;
  int C = half ? C2 : C5;
  unsigned int v = 0;
  if (rr <= C) {
    // cache up to 4 candidates/lane in regs (0-pad: 0 is never >= cth >= 1)
    unsigned int rc0 = (hl < C) ? cd[hl] : 0u;
    unsigned int rc1 = (hl + 32 < C) ? cd[hl + 32] : 0u;
    unsigned int rc2 = (hl + 64 < C) ? cd[hl + 64] : 0u;
    unsigned int rc3 = (hl + 96 < C) ? cd[hl + 96] : 0u;
    v = bb << 21;
    for (int bit = 20; bit >= 0; --bit) {
      unsigned int cth = v | (1u << bit);
      int cnt = ((rc0 >= cth) ? 1 : 0) + ((rc1 >= cth) ? 1 : 0) +
                ((rc2 >= cth) ? 1 : 0) + ((rc3 >= cth) ? 1 : 0);
      for (int p = hl + 128; p < C; p += 32) cnt += (cd[p] >= cth) ? 1 : 0;
#pragma unroll
      for (int d = 1; d < 32; d <<= 1) cnt += __shfl_xor(cnt, d, 64);
      if (cnt >= rr) v = cth;
    }
  }
  const unsigned int v512 = (unsigned int)__shfl((int)v, 0, 64);
  const unsigned int v256 = (unsigned int)__shfl((int)v, 32, 64);

  int g = 0, e = 0;
#pragma unroll
  for (int s = 0; s < 8; ++s)
#pragma unroll
    for (int c = 0; c < 4; ++c) {
      g += (key[s][c] > v512) ? 1 : 0;
      g += (key[s][c] > v256) ? (1 << 16) : 0;
      e += (key[s][c] == v512) ? 1 : 0;
      e += (key[s][c] == v256) ? (1 << 16) : 0;
    }
#pragma unroll
  for (int d = 1; d < 64; d <<= 1) {
    g += __shfl_xor(g, d, 64);
    e += __shfl_xor(e, d, 64);
  }
  const int rg512 = 512 - (g & 0xffff);
  const int rg256 = 256 - (g >> 16);
  const int e512 = e & 0xffff;
  const int e256 = e >> 16;

  if (e512 == rg512 && e256 == rg256) {
    // fast path: all boundary ties selected -> share/cur = (key >= v)
#pragma unroll
    for (int s = 0; s < 8; ++s) {
      float mpn[4];
      unsigned int hb0 = hvb[s].x, hb1 = hvb[s].y;
#pragma unroll
      for (int c = 0; c < 4; ++c) {
        unsigned int k = key[s][c];
        bool share = (k >= v512);
        bool cur = (k >= v256);
        int mm = (mmbits >> (s * 4 + c)) & 1;
        mpn[c] = (float)mm + (cur ? 1.0f : 0.0f);
        if (!share) {
          if (c == 0) hb0 &= 0xffff0000u;
          if (c == 1) hb0 &= 0x0000ffffu;
          if (c == 2) hb1 &= 0xffff0000u;
          if (c == 3) hb1 &= 0x0000ffffu;
        }
      }
      float4 so = {mpn[0], mpn[1], mpn[2], mpn[3]};
      *(float4*)(hrow + (s * 64 + lane) * 4) = so;
      uint2 ho = {hb0, hb1};
      *(uint2*)(hsrow + (s * 64 + lane) * 4) = ho;
    }
  } else {
    // slow path: exact index-order tie ranking (verified R5 logic)
    int excl = 0;
#pragma unroll
    for (int s = 0; s < 8; ++s) {
      int tcnt = 0;
#pragma unroll
      for (int c = 0; c < 4; ++c) {
        tcnt += (key[s][c] == v512) ? 1 : 0;
        tcnt += (key[s][c] == v256) ? (1 << 16) : 0;
      }
      int incl = tcnt;
#pragma unroll
      for (int d = 1; d < 64; d <<= 1) {
        int o = __shfl_up(incl, d, 64);
        if (lane >= d) incl += o;
      }
      int myexcl = excl + incl - tcnt;
      int tot = __shfl(incl, 63, 64);
      int run512 = myexcl & 0xffff;
      int run256 = (myexcl >> 16) & 0xffff;
      float mpn[4];
      unsigned int hb0 = hvb[s].x, hb1 = hvb[s].y;
#pragma unroll
      for (int c = 0; c < 4; ++c) {
        unsigned int k = key[s][c];
        bool share, cur;
        if (k > v512) share = true;
        else if (k == v512) { share = (run512 < rg512); run512++; }
        else share = false;
        if (k > v256) cur = true;
        else if (k == v256) { cur = (run256 < rg256); run256++; }
        else cur = false;
        int mm = (mmbits >> (s * 4 + c)) & 1;
        mpn[c] = (float)mm + (cur ? 1.0f : 0.0f);
        if (!share) {
          if (c == 0) hb0 &= 0xffff0000u;
          if (c == 1) hb0 &= 0x0000ffffu;
          if (c == 2) hb1 &= 0xffff0000u;
          if (c == 3) hb1 &= 0x0000ffffu;
        }
      }
      float4 so = {mpn[0], mpn[1], mpn[2], mpn[3]};
      *(float4*)(hrow + (s * 64 + lane) * 4) = so;
      uint2 ho = {hb0, hb1};
      *(uint2*)(hsrow + (s * 64 + lane) * 4) = ho;
      excl += tot;
    }
  }
}

// ---------------- GEMM2: out = hs @ W_dec^T + b_dec (bf16 MFMA) ----------------
// Round-6 measured config (<=122 us bound): 64x128 tile, BK=32, 1024 blocks
// (4/CU), 2x2 waves, LDS stride 40 shorts (conflict-free), register prefetch.
// + fused W_dec f32->bf16 conversion in staging (same f2bf RNE -> bitwise
// identical operands; removes the cvt kernel + one launch).
// BK=64 variants measured 3x slower (rounds 2/3/7) — do not revisit.
__global__ __launch_bounds__(256) void gemm2_kernel(
    const unsigned short* __restrict__ A,  // hs bf16 [M, HDIM]
    const float* __restrict__ Wd,          // W_dec f32 [ODIM, HDIM]
    const float* __restrict__ bdec,        // [ODIM]
    float* __restrict__ out) {             // [M, ODIM] f32
  __shared__ __align__(16) unsigned short As[64 * 40];
  __shared__ __align__(16) unsigned short Bs[128 * 40];
  const int t = threadIdx.x;
  const int lane = t & 63;
  const int w = t >> 6;
  const int wm = w >> 1, wn = w & 1;
  const int m0 = blockIdx.y * 64;
  const int n0 = blockIdx.x * 128;
  const int r = t >> 2;          // staging row 0..63
  const int k8 = (t & 3) * 8;

  f32x4 acc[2][4];
#pragma unroll
  for (int i = 0; i < 2; ++i)
#pragma unroll
    for (int j = 0; j < 4; ++j) acc[i][j] = (f32x4){0.f, 0.f, 0.f, 0.f};

  const int la = lane & 15;
  const int kq = (lane >> 4) * 8;

  const unsigned short* pa = A + (size_t)(m0 + r) * HDIM + k8;
  const float* pb0 = Wd + (size_t)(n0 + r) * HDIM + k8;
  const float* pb1 = Wd + (size_t)(n0 + 64 + r) * HDIM + k8;

  uint4 a0 = *(const uint4*)(pa);
  float4 b0a = *(const float4*)(pb0);
  float4 b0b = *(const float4*)(pb0 + 4);
  float4 b1a = *(const float4*)(pb1);
  float4 b1b = *(const float4*)(pb1 + 4);

  for (int kt = 0; kt < HDIM; kt += 32) {
    __syncthreads();
    *(uint4*)&As[r * 40 + k8] = a0;
    *(uint4*)&Bs[r * 40 + k8] = pack8bf(b0a, b0b);
    *(uint4*)&Bs[(64 + r) * 40 + k8] = pack8bf(b1a, b1b);
    __syncthreads();
    if (kt + 32 < HDIM) {
      a0 = *(const uint4*)(pa + kt + 32);
      b0a = *(const float4*)(pb0 + kt + 32);
      b0b = *(const float4*)(pb0 + kt + 36);
      b1a = *(const float4*)(pb1 + kt + 32);
      b1b = *(const float4*)(pb1 + kt + 36);
    }
    bf16x8 af[2], bg[4];
#pragma unroll
    for (int mi = 0; mi < 2; ++mi)
      af[mi] = *(const bf16x8*)&As[(wm * 32 + mi * 16 + la) * 40 + kq];
#pragma unroll
    for (int ni = 0; ni < 4; ++ni)
      bg[ni] = *(const bf16x8*)&Bs[(wn * 64 + ni * 16 + la) * 40 + kq];
#pragma unroll
    for (int mi = 0; mi < 2; ++mi)
#pragma unroll
      for (int ni = 0; ni < 4; ++ni)
        acc[mi][ni] = __builtin_amdgcn_mfma_f32_16x16x32_bf16(
            af[mi], bg[ni], acc[mi][ni], 0, 0, 0);
  }
  // C/D: col = lane&15, row = (lane>>4)*4 + reg
  const int rq = (lane >> 4) * 4;
#pragma unroll
  for (int mi = 0; mi < 2; ++mi) {
#pragma unroll
    for (int ni = 0; ni < 4; ++ni) {
      int n = n0 + wn * 64 + ni * 16 + la;
      float bd = bdec[n];
#pragma unroll
      for (int rr = 0; rr < 4; ++rr) {
        int m = m0 + wm * 32 + mi * 16 + rq + rr;
        out[(size_t)m * ODIM + n] = acc[mi][ni][rr] + bd;
      }
    }
  }
}

extern "C" void kernel_launch(void* const* d_in, const int* in_sizes, int n_in,
                              void* d_out, int out_size, void* d_ws, size_t ws_size,
                              hipStream_t stream) {
  const float* x = (const float*)d_in[0];
  const int* mask_prev = (const int*)d_in[1];
  const float* W_enc = (const float*)d_in[2];
  const float* b_enc = (const float*)d_in[3];
  const float* W_dec = (const float*)d_in[4];
  const float* b_dec = (const float*)d_in[5];

  float* out = (float*)d_out;
  float* hbuf = out + (size_t)MDIM * ODIM;     // h / mask_prev_new slot
  unsigned short* hs = (unsigned short*)d_ws;  // [M, HDIM] bf16

  gemm1_kernel<<<dim3(HDIM / 128, MDIM / 128), dim3(256), 0, stream>>>(
      x, W_enc, b_enc, hbuf);
  select_kernel<<<dim3(MDIM / 4), dim3(256), 0, stream>>>(hbuf, mask_prev, hs);
  gemm2_kernel<<<dim3(ODIM / 128, MDIM / 64), dim3(256), 0, stream>>>(
      hs, W_dec, b_dec, out);
}

// Round 10
// 739.070 us; speedup vs baseline: 1.0215x; 1.0215x over previous
//
#include <hip/hip_runtime.h>
#include <hip/hip_bf16.h>

typedef __attribute__((ext_vector_type(8))) __bf16 bf16x8;
typedef __attribute__((ext_vector_type(4))) float f32x4;

#define MDIM 16384  // B*T
#define HDIM 2048
#define IDIM 512
#define ODIM 512
#define SCAP 512    // per-bin candidate cap

static __device__ __forceinline__ unsigned short f2bf(float f) {
  unsigned int u = __float_as_uint(f);
  unsigned int r = (u + 0x7fffu + ((u >> 16) & 1u)) >> 16;
  return (unsigned short)r;
}

// ---------------- W_dec f32 -> bf16 (separate kernel; fusing into gemm2
// staging measured ~neutral-negative: f32 B-reads double L2 traffic) --------
__global__ void cvt_bf16_kernel(const float* __restrict__ src,
                                unsigned short* __restrict__ dst, int n) {
  int i = (blockIdx.x * 256 + threadIdx.x) * 4;
  if (i >= n) return;
  float4 v = *(const float4*)(src + i);
  unsigned int a = (unsigned int)f2bf(v.x) | ((unsigned int)f2bf(v.y) << 16);
  unsigned int b = (unsigned int)f2bf(v.z) | ((unsigned int)f2bf(v.w) << 16);
  uint2 st; st.x = a; st.y = b;
  *(uint2*)(dst + i) = st;
}

// ---------------- GEMM1: h = x @ W_enc^T + b_enc (f32) ----------------
// Round-0 version exactly: 128x128 tile, BK=32, 8x8 micro-tile, NO prefetch.
// Measured 381-396 us (6 runs), VGPR 72, VALU 76-77%. Runs at 87% of the
// measured scalar-FMA chip rate (m07: 103 TF); LDS/VALU co-saturation
// equilibrium. Prefetch (+VGPR) and 8x16 (spill) both measured worse. Done.
__global__ __launch_bounds__(256) void gemm1_kernel(
    const float* __restrict__ x,     // [M, IDIM]
    const float* __restrict__ wenc,  // [HDIM, IDIM]
    const float* __restrict__ benc,  // [HDIM]
    float* __restrict__ h) {         // [M, HDIM]
  __shared__ __align__(16) float As[32][132];  // [k][m], +4 pad
  __shared__ __align__(16) float Bs[32][132];  // [k][n]
  const int t = threadIdx.x;
  const int tx = t & 15, ty = t >> 4;
  const int m0 = blockIdx.y * 128;
  const int n0 = blockIdx.x * 128;
  const int r0 = t >> 1;          // 0..127 staging row
  const int kh = (t & 1) * 16;    // k sub-offset (0 or 16)

  const float* pa = x + (size_t)(m0 + r0) * IDIM + kh;
  const float* pb = wenc + (size_t)(n0 + r0) * IDIM + kh;

  float acc[8][8];
#pragma unroll
  for (int i = 0; i < 8; ++i)
#pragma unroll
    for (int j = 0; j < 8; ++j) acc[i][j] = 0.f;

  for (int kt = 0; kt < IDIM; kt += 32) {
    float4 a0 = *(const float4*)(pa + kt);
    float4 a1 = *(const float4*)(pa + kt + 4);
    float4 a2 = *(const float4*)(pa + kt + 8);
    float4 a3 = *(const float4*)(pa + kt + 12);
    float4 b0 = *(const float4*)(pb + kt);
    float4 b1 = *(const float4*)(pb + kt + 4);
    float4 b2 = *(const float4*)(pb + kt + 8);
    float4 b3 = *(const float4*)(pb + kt + 12);
    __syncthreads();
    {
      const float av[16] = {a0.x, a0.y, a0.z, a0.w, a1.x, a1.y, a1.z, a1.w,
                            a2.x, a2.y, a2.z, a2.w, a3.x, a3.y, a3.z, a3.w};
      const float bv[16] = {b0.x, b0.y, b0.z, b0.w, b1.x, b1.y, b1.z, b1.w,
                            b2.x, b2.y, b2.z, b2.w, b3.x, b3.y, b3.z, b3.w};
#pragma unroll
      for (int j = 0; j < 16; ++j) {
        As[kh + j][r0] = av[j];
        Bs[kh + j][r0] = bv[j];
      }
    }
    __syncthreads();
#pragma unroll
    for (int k = 0; k < 32; ++k) {
      float4 av0 = *(const float4*)&As[k][ty * 4];
      float4 av1 = *(const float4*)&As[k][64 + ty * 4];
      float4 bv0 = *(const float4*)&Bs[k][tx * 4];
      float4 bv1 = *(const float4*)&Bs[k][64 + tx * 4];
      float am[8] = {av0.x, av0.y, av0.z, av0.w, av1.x, av1.y, av1.z, av1.w};
      float bm[8] = {bv0.x, bv0.y, bv0.z, bv0.w, bv1.x, bv1.y, bv1.z, bv1.w};
#pragma unroll
      for (int i = 0; i < 8; ++i)
#pragma unroll
        for (int j = 0; j < 8; ++j) acc[i][j] += am[i] * bm[j];
    }
  }
  float4 be0 = *(const float4*)(benc + n0 + tx * 4);
  float4 be1 = *(const float4*)(benc + n0 + 64 + tx * 4);
  float bb[8] = {be0.x, be0.y, be0.z, be0.w, be1.x, be1.y, be1.z, be1.w};
#pragma unroll
  for (int i = 0; i < 8; ++i) {
    int m = m0 + ((i < 4) ? (ty * 4 + i) : (64 + ty * 4 + (i - 4)));
    float* hrow = h + (size_t)m * HDIM + n0;
    float4 s0 = {acc[i][0] + bb[0], acc[i][1] + bb[1], acc[i][2] + bb[2], acc[i][3] + bb[3]};
    float4 s1 = {acc[i][4] + bb[4], acc[i][5] + bb[5], acc[i][6] + bb[6], acc[i][7] + bb[7]};
    *(float4*)(hrow + tx * 4) = s0;
    *(float4*)(hrow + 64 + tx * 4) = s1;
  }
}

// ---------------- selection v5: wave-per-row, barrier-free ------------------
// v4 (measured 123 us) + reg-cached refine + tie fast path (common case:
// all boundary ties selected -> share/cur = (key >= v), rank phase skipped;
// degenerate v==0 provably falls to the verified rank logic).
__global__ __launch_bounds__(256, 4) void select_kernel(
    float* __restrict__ hbuf,           // in: raw h [M,HDIM]; out: mask_prev_new
    const int* __restrict__ maskp,      // [M, HDIM]
    unsigned short* __restrict__ hs) {  // out: h*mask_share as bf16 [M,HDIM]
  const int t = threadIdx.x;
  const int lane = t & 63;
  const int w = t >> 6;
  const int row = blockIdx.x * 4 + w;

  __shared__ int hist[4][1024];               // 16 KB, wave-private slices
  __shared__ unsigned int cand[4][2][SCAP];   // 16 KB
  __shared__ int nc[4][2];

  int* H = hist[w];
  float* hrow = hbuf + (size_t)row * HDIM;
  const int* mrow = maskp + (size_t)row * HDIM;
  unsigned short* hsrow = hs + (size_t)row * HDIM;

  {
    int4 z = {0, 0, 0, 0};
#pragma unroll
    for (int i = 0; i < 4; ++i) *(int4*)&H[(i * 64 + lane) * 4] = z;
  }
  if (lane == 0) { nc[w][0] = 0; nc[w][1] = 0; }

  unsigned int key[8][4];
  uint2 hvb[8];
  unsigned int mmbits = 0;
#pragma unroll
  for (int s = 0; s < 8; ++s) {
    float4 hv = *(const float4*)(hrow + (s * 64 + lane) * 4);
    int4 mv = *(const int4*)(mrow + (s * 64 + lane) * 4);
    float h0 = (mv.x > 0) ? 0.f : hv.x;
    float h1 = (mv.y > 0) ? 0.f : hv.y;
    float h2 = (mv.z > 0) ? 0.f : hv.z;
    float h3 = (mv.w > 0) ? 0.f : hv.w;
    mmbits |= ((mv.x > 0) ? 1u : 0u) << (s * 4 + 0);
    mmbits |= ((mv.y > 0) ? 1u : 0u) << (s * 4 + 1);
    mmbits |= ((mv.z > 0) ? 1u : 0u) << (s * 4 + 2);
    mmbits |= ((mv.w > 0) ? 1u : 0u) << (s * 4 + 3);
    key[s][0] = __float_as_uint(h0 * h0);
    key[s][1] = __float_as_uint(h1 * h1);
    key[s][2] = __float_as_uint(h2 * h2);
    key[s][3] = __float_as_uint(h3 * h3);
    hvb[s].x = (unsigned int)f2bf(h0) | ((unsigned int)f2bf(h1) << 16);
    hvb[s].y = (unsigned int)f2bf(h2) | ((unsigned int)f2bf(h3) << 16);
  }

#pragma unroll
  for (int s = 0; s < 8; ++s)
#pragma unroll
    for (int c = 0; c < 4; ++c)
      if (key[s][c]) atomicAdd(&H[key[s][c] >> 21], 1);

  int q[16];
#pragma unroll
  for (int i = 0; i < 16; i += 4) {
    int4 hh = *(const int4*)&H[lane * 16 + i];
    q[i] = hh.x; q[i + 1] = hh.y; q[i + 2] = hh.z; q[i + 3] = hh.w;
  }
  int ls = 0;
#pragma unroll
  for (int i = 0; i < 16; ++i) ls += q[i];
  int rs = ls;
#pragma unroll
  for (int d = 1; d < 64; d <<= 1) {
    int o = __shfl_down(rs, d, 64);
    rs += (lane + d < 64) ? o : 0;
  }
  int f512 = -1, f256 = -1;
  {
    int c = rs - ls;
#pragma unroll
    for (int i = 15; i >= 0; --i) {
      int hc = q[i];
      if (c < 512 && c + hc >= 512) f512 = ((lane * 16 + i) << 12) | (512 - c);
      if (c < 256 && c + hc >= 256) f256 = ((lane * 16 + i) << 12) | (256 - c);
      c += hc;
    }
  }
#pragma unroll
  for (int d = 1; d < 64; d <<= 1) {
    f512 = max(f512, __shfl_xor(f512, d, 64));
    f256 = max(f256, __shfl_xor(f256, d, 64));
  }
  int b512, rb512, b256, rb256;
  if (f512 < 0) { b512 = 0; rb512 = 0x40000000; } else { b512 = f512 >> 12; rb512 = f512 & 0xfff; }
  if (f256 < 0) { b256 = 0; rb256 = 0x40000000; } else { b256 = f256 >> 12; rb256 = f256 & 0xfff; }

  unsigned int* c5 = cand[w][0];
  unsigned int* c2 = cand[w][1];
#pragma unroll
  for (int s = 0; s < 8; ++s)
#pragma unroll
    for (int c = 0; c < 4; ++c) {
      unsigned int k = key[s][c];
      if (k) {
        int bin = (int)(k >> 21);
        if (bin == b512) { int p = atomicAdd(&nc[w][0], 1); if (p < SCAP) c5[p] = k; }
        if (bin == b256) { int p = atomicAdd(&nc[w][1], 1); if (p < SCAP) c2[p] = k; }
      }
    }
  int C5 = nc[w][0]; C5 = (C5 < SCAP) ? C5 : SCAP;
  int C2 = nc[w][1]; C2 = (C2 < SCAP) ? C2 : SCAP;

  const int half = lane >> 5;
  const int hl = lane & 31;
  unsigned int bb = half ? (unsigned int)b256 : (unsigned int)b512;
  int rr = half ? rb256 : rb512;
  const unsigned int* cd = half ? c2 : c5;
  int C = half ? C2 : C5;
  unsigned int v = 0;
  if (rr <= C) {
    unsigned int rc0 = (hl < C) ? cd[hl] : 0u;
    unsigned int rc1 = (hl + 32 < C) ? cd[hl + 32] : 0u;
    unsigned int rc2 = (hl + 64 < C) ? cd[hl + 64] : 0u;
    unsigned int rc3 = (hl + 96 < C) ? cd[hl + 96] : 0u;
    v = bb << 21;
    for (int bit = 20; bit >= 0; --bit) {
      unsigned int cth = v | (1u << bit);
      int cnt = ((rc0 >= cth) ? 1 : 0) + ((rc1 >= cth) ? 1 : 0) +
                ((rc2 >= cth) ? 1 : 0) + ((rc3 >= cth) ? 1 : 0);
      for (int p = hl + 128; p < C; p += 32) cnt += (cd[p] >= cth) ? 1 : 0;
#pragma unroll
      for (int d = 1; d < 32; d <<= 1) cnt += __shfl_xor(cnt, d, 64);
      if (cnt >= rr) v = cth;
    }
  }
  const unsigned int v512 = (unsigned int)__shfl((int)v, 0, 64);
  const unsigned int v256 = (unsigned int)__shfl((int)v, 32, 64);

  int g = 0, e = 0;
#pragma unroll
  for (int s = 0; s < 8; ++s)
#pragma unroll
    for (int c = 0; c < 4; ++c) {
      g += (key[s][c] > v512) ? 1 : 0;
      g += (key[s][c] > v256) ? (1 << 16) : 0;
      e += (key[s][c] == v512) ? 1 : 0;
      e += (key[s][c] == v256) ? (1 << 16) : 0;
    }
#pragma unroll
  for (int d = 1; d < 64; d <<= 1) {
    g += __shfl_xor(g, d, 64);
    e += __shfl_xor(e, d, 64);
  }
  const int rg512 = 512 - (g & 0xffff);
  const int rg256 = 256 - (g >> 16);
  const int e512 = e & 0xffff;
  const int e256 = e >> 16;

  if (e512 == rg512 && e256 == rg256) {
    // fast path: all boundary ties selected -> share/cur = (key >= v)
#pragma unroll
    for (int s = 0; s < 8; ++s) {
      float mpn[4];
      unsigned int hb0 = hvb[s].x, hb1 = hvb[s].y;
#pragma unroll
      for (int c = 0; c < 4; ++c) {
        unsigned int k = key[s][c];
        bool share = (k >= v512);
        bool cur = (k >= v256);
        int mm = (mmbits >> (s * 4 + c)) & 1;
        mpn[c] = (float)mm + (cur ? 1.0f : 0.0f);
        if (!share) {
          if (c == 0) hb0 &= 0xffff0000u;
          if (c == 1) hb0 &= 0x0000ffffu;
          if (c == 2) hb1 &= 0xffff0000u;
          if (c == 3) hb1 &= 0x0000ffffu;
        }
      }
      float4 so = {mpn[0], mpn[1], mpn[2], mpn[3]};
      *(float4*)(hrow + (s * 64 + lane) * 4) = so;
      uint2 ho = {hb0, hb1};
      *(uint2*)(hsrow + (s * 64 + lane) * 4) = ho;
    }
  } else {
    // slow path: exact index-order tie ranking (verified R5 logic)
    int excl = 0;
#pragma unroll
    for (int s = 0; s < 8; ++s) {
      int tcnt = 0;
#pragma unroll
      for (int c = 0; c < 4; ++c) {
        tcnt += (key[s][c] == v512) ? 1 : 0;
        tcnt += (key[s][c] == v256) ? (1 << 16) : 0;
      }
      int incl = tcnt;
#pragma unroll
      for (int d = 1; d < 64; d <<= 1) {
        int o = __shfl_up(incl, d, 64);
        if (lane >= d) incl += o;
      }
      int myexcl = excl + incl - tcnt;
      int tot = __shfl(incl, 63, 64);
      int run512 = myexcl & 0xffff;
      int run256 = (myexcl >> 16) & 0xffff;
      float mpn[4];
      unsigned int hb0 = hvb[s].x, hb1 = hvb[s].y;
#pragma unroll
      for (int c = 0; c < 4; ++c) {
        unsigned int k = key[s][c];
        bool share, cur;
        if (k > v512) share = true;
        else if (k == v512) { share = (run512 < rg512); run512++; }
        else share = false;
        if (k > v256) cur = true;
        else if (k == v256) { cur = (run256 < rg256); run256++; }
        else cur = false;
        int mm = (mmbits >> (s * 4 + c)) & 1;
        mpn[c] = (float)mm + (cur ? 1.0f : 0.0f);
        if (!share) {
          if (c == 0) hb0 &= 0xffff0000u;
          if (c == 1) hb0 &= 0x0000ffffu;
          if (c == 2) hb1 &= 0xffff0000u;
          if (c == 3) hb1 &= 0x0000ffffu;
        }
      }
      float4 so = {mpn[0], mpn[1], mpn[2], mpn[3]};
      *(float4*)(hrow + (s * 64 + lane) * 4) = so;
      uint2 ho = {hb0, hb1};
      *(uint2*)(hsrow + (s * 64 + lane) * 4) = ho;
      excl += tot;
    }
  }
}

// ---------------- GEMM2: out = hs @ W_dec^T + b_dec (bf16 MFMA) ----------------
// R6/R8-measured config exactly (<=122 us bound): 64x128 tile, BK=32, 1024
// blocks (4/CU), 2x2 waves, LDS stride 40 shorts (conflict-free), register
// prefetch, bf16 B from workspace. BK=64 measured 3x slower (r2/3/7); f32
// B-read fusion measured ~neutral-negative (r9). Do not revisit.
__global__ __launch_bounds__(256) void gemm2_kernel(
    const unsigned short* __restrict__ A,  // hs bf16 [M, HDIM]
    const unsigned short* __restrict__ B,  // W_dec bf16 [ODIM, HDIM]
    const float* __restrict__ bdec,        // [ODIM]
    float* __restrict__ out) {             // [M, ODIM] f32
  __shared__ __align__(16) unsigned short As[64 * 40];
  __shared__ __align__(16) unsigned short Bs[128 * 40];
  const int t = threadIdx.x;
  const int lane = t & 63;
  const int w = t >> 6;
  const int wm = w >> 1, wn = w & 1;
  const int m0 = blockIdx.y * 64;
  const int n0 = blockIdx.x * 128;
  const int r = t >> 2;          // staging row 0..63
  const int k8 = (t & 3) * 8;

  f32x4 acc[2][4];
#pragma unroll
  for (int i = 0; i < 2; ++i)
#pragma unroll
    for (int j = 0; j < 4; ++j) acc[i][j] = (f32x4){0.f, 0.f, 0.f, 0.f};

  const int la = lane & 15;
  const int kq = (lane >> 4) * 8;

  const unsigned short* pa = A + (size_t)(m0 + r) * HDIM + k8;
  const unsigned short* pb0 = B + (size_t)(n0 + r) * HDIM + k8;
  const unsigned short* pb1 = B + (size_t)(n0 + 64 + r) * HDIM + k8;

  uint4 a0 = *(const uint4*)(pa);
  uint4 b0 = *(const uint4*)(pb0);
  uint4 b1 = *(const uint4*)(pb1);

  for (int kt = 0; kt < HDIM; kt += 32) {
    __syncthreads();
    *(uint4*)&As[r * 40 + k8] = a0;
    *(uint4*)&Bs[r * 40 + k8] = b0;
    *(uint4*)&Bs[(64 + r) * 40 + k8] = b1;
    __syncthreads();
    if (kt + 32 < HDIM) {
      a0 = *(const uint4*)(pa + kt + 32);
      b0 = *(const uint4*)(pb0 + kt + 32);
      b1 = *(const uint4*)(pb1 + kt + 32);
    }
    bf16x8 af[2], bg[4];
#pragma unroll
    for (int mi = 0; mi < 2; ++mi)
      af[mi] = *(const bf16x8*)&As[(wm * 32 + mi * 16 + la) * 40 + kq];
#pragma unroll
    for (int ni = 0; ni < 4; ++ni)
      bg[ni] = *(const bf16x8*)&Bs[(wn * 64 + ni * 16 + la) * 40 + kq];
#pragma unroll
    for (int mi = 0; mi < 2; ++mi)
#pragma unroll
      for (int ni = 0; ni < 4; ++ni)
        acc[mi][ni] = __builtin_amdgcn_mfma_f32_16x16x32_bf16(
            af[mi], bg[ni], acc[mi][ni], 0, 0, 0);
  }
  // C/D: col = lane&15, row = (lane>>4)*4 + reg
  const int rq = (lane >> 4) * 4;
#pragma unroll
  for (int mi = 0; mi < 2; ++mi) {
#pragma unroll
    for (int ni = 0; ni < 4; ++ni) {
      int n = n0 + wn * 64 + ni * 16 + la;
      float bd = bdec[n];
#pragma unroll
      for (int rr = 0; rr < 4; ++rr) {
        int m = m0 + wm * 32 + mi * 16 + rq + rr;
        out[(size_t)m * ODIM + n] = acc[mi][ni][rr] + bd;
      }
    }
  }
}

extern "C" void kernel_launch(void* const* d_in, const int* in_sizes, int n_in,
                              void* d_out, int out_size, void* d_ws, size_t ws_size,
                              hipStream_t stream) {
  const float* x = (const float*)d_in[0];
  const int* mask_prev = (const int*)d_in[1];
  const float* W_enc = (const float*)d_in[2];
  const float* b_enc = (const float*)d_in[3];
  const float* W_dec = (const float*)d_in[4];
  const float* b_dec = (const float*)d_in[5];

  float* out = (float*)d_out;
  float* hbuf = out + (size_t)MDIM * ODIM;          // h / mask_prev_new slot
  unsigned short* hs = (unsigned short*)d_ws;       // [M, HDIM] bf16
  unsigned short* wdec = hs + (size_t)MDIM * HDIM;  // [ODIM, HDIM] bf16

  cvt_bf16_kernel<<<dim3((ODIM * HDIM) / (256 * 4)), dim3(256), 0, stream>>>(
      W_dec, wdec, ODIM * HDIM);
  gemm1_kernel<<<dim3(HDIM / 128, MDIM / 128), dim3(256), 0, stream>>>(
      x, W_enc, b_enc, hbuf);
  select_kernel<<<dim3(MDIM / 4), dim3(256), 0, stream>>>(hbuf, mask_prev, hs);
  gemm2_kernel<<<dim3(ODIM / 128, MDIM / 64), dim3(256), 0, stream>>>(
      hs, wdec, b_dec, out);
}